// Round 2
// baseline (225.121 us; speedup 1.0000x reference)
//
#include <hip/hip_runtime.h>
#include <math.h>

#define HW     76800
#define HW4    19200
#define NCH    86
#define OCH    89
#define NB     4
#define THRESHF 0.7f
#define BIGF   1e30f

typedef float f4 __attribute__((ext_vector_type(4)));

// ws float layout:
// [0..63]    votes: b*16 + j*7 + {0:denom, 1..3:loc, 4..6:rot}
// [64..207]  M:     (b*3 + k)*12 row-major 3x4 [R|t]
// [256..279] minmax keys (uint32): b*6 + c   (0..2 low, 3..5 up)
// [288..319] prep:  b*8 + {0..2 low, 3 safe, 4 flag, 5 fl0(int bits)}

__device__ __forceinline__ float sigmoidf_(float x) {
    if (x >= 0.f) { return 1.f / (1.f + expf(-x)); }
    float e = expf(x); return e / (1.f + e);
}
__device__ __forceinline__ unsigned fkey(float f) {
    unsigned u = __float_as_uint(f);
    return (u & 0x80000000u) ? ~u : (u | 0x80000000u);
}
__device__ __forceinline__ float funkey(unsigned k) {
    unsigned u = (k & 0x80000000u) ? (k ^ 0x80000000u) : ~k;
    return __uint_as_float(u);
}
__device__ __forceinline__ int vox1(float q) {
    int v = (int)floorf(q * 32.f);
    return v < 0 ? 0 : (v > 31 ? 31 : v);
}

__global__ __launch_bounds__(256) void k_votes(const float* __restrict__ in,
                                               float* __restrict__ ws) {
    const int b = blockIdx.y;
    const int p = blockIdx.x * 256 + threadIdx.x;
    const float* ib = in + (size_t)b * NCH * HW + p;
    float m  = sigmoidf_(ib[(size_t)3 * HW]);
    float s0 = sigmoidf_(ib[(size_t)20 * HW]) * m;
    float s1 = sigmoidf_(ib[(size_t)21 * HW]) * m;
    float w0 = m * s0, w1 = m * s1;
    float acc[14];
    acc[0] = s0; acc[7] = s1;
#pragma unroll
    for (int c = 0; c < 3; c++) {
        acc[1 + c]  = ib[(size_t)(4 + c)  * HW] * w0;   // loc j0
        acc[8 + c]  = ib[(size_t)(7 + c)  * HW] * w1;   // loc j1
        acc[4 + c]  = ib[(size_t)(10 + c) * HW] * w0;   // rot j0
        acc[11 + c] = ib[(size_t)(13 + c) * HW] * w1;   // rot j1
    }
    __shared__ float red[4][14];
    int lane = threadIdx.x & 63, wid = threadIdx.x >> 6;
#pragma unroll
    for (int i = 0; i < 14; i++) {
        float v = acc[i];
        for (int off = 32; off > 0; off >>= 1) v += __shfl_down(v, off, 64);
        if (lane == 0) red[wid][i] = v;
    }
    __syncthreads();
    if (threadIdx.x < 14) {
        float s = red[0][threadIdx.x] + red[1][threadIdx.x] +
                  red[2][threadIdx.x] + red[3][threadIdx.x];
        atomicAdd(&ws[b * 16 + threadIdx.x], s);
    }
}

__global__ void k_build(float* __restrict__ ws) {
    int tid = threadIdx.x;
    if (tid < 12) {
        int b = tid / 3, k = tid % 3;
        float lp0 = 0, lp1 = 0, lp2 = 0, rp0 = 0, rp1 = 0, rp2 = 0;
        if (k > 0) {
            const float* v = ws + b * 16 + (k - 1) * 7;
            float d = v[0] + 1e-5f;
            lp0 = v[1] / d; lp1 = v[2] / d; lp2 = v[3] / d;
            rp0 = v[4] / d; rp1 = v[5] / d; rp2 = v[6] / d;
        }
        float rx = -rp0, ry = -rp1, rz = -rp2;
        float ang = sqrtf(rx * rx + ry * ry + rz * rz) + 1e-8f;
        float ax = rx / ang, ay = ry / ang, az = rz / ang;
        float K[3][3] = {{0.f, -az, ay}, {az, 0.f, -ax}, {-ay, ax, 0.f}};
        float c = cosf(ang), s = sinf(ang);
        float K2[3][3], Rm[3][3];
#pragma unroll
        for (int i = 0; i < 3; i++)
#pragma unroll
            for (int j = 0; j < 3; j++)
                K2[i][j] = K[i][0] * K[0][j] + K[i][1] * K[1][j] + K[i][2] * K[2][j];
#pragma unroll
        for (int i = 0; i < 3; i++)
#pragma unroll
            for (int j = 0; j < 3; j++)
                Rm[i][j] = (i == j ? 1.f : 0.f) + s * K[i][j] + (1.f - c) * K2[i][j];
        float t0 = lp0, t1 = lp1, t2 = lp2;
        float* M = ws + 64 + (b * 3 + k) * 12;
#pragma unroll
        for (int i = 0; i < 3; i++) {
            M[i * 4 + 0] = Rm[i][0]; M[i * 4 + 1] = Rm[i][1]; M[i * 4 + 2] = Rm[i][2];
            float tt = (i == 0 ? t0 : (i == 1 ? t1 : t2));
            M[i * 4 + 3] = tt - (Rm[i][0] * t0 + Rm[i][1] * t1 + Rm[i][2] * t2);
        }
    }
    if (tid >= 12 && tid < 36) {
        int s2 = tid - 12;
        unsigned* keys = (unsigned*)(ws + 256);
        keys[s2] = ((s2 % 6) < 3) ? fkey(BIGF) : fkey(-BIGF);
    }
}

__global__ __launch_bounds__(256) void k_minmax(const float* __restrict__ in,
                                                float* __restrict__ ws) {
    const int b = blockIdx.y;
    const int p = blockIdx.x * 256 + threadIdx.x;
    const float* ib = in + (size_t)b * NCH * HW + p;
    const float* Mb = ws + 64 + b * 36;
    float mn[3] = {BIGF, BIGF, BIGF}, mx[3] = {-BIGF, -BIGF, -BIGF};
    float m = sigmoidf_(ib[(size_t)3 * HW]);
    if (m > THRESHF) {
        float v0 = ib[(size_t)16 * HW], v1 = ib[(size_t)17 * HW];
        float v2 = ib[(size_t)18 * HW], v3 = ib[(size_t)19 * HW];
        int am = 0; float bb = v0;
        if (v1 > bb) { bb = v1; am = 1; }
        if (v2 > bb) { bb = v2; am = 2; }
        if (v3 > bb) { bb = v3; am = 3; }
        float px = 0.f, py = 0.f, pz = 0.f;
        if (am > 0) {
            const float* Mk = Mb + (am - 1) * 12;
            float a = ib[0], bq = ib[(size_t)HW], cq = ib[(size_t)2 * HW];
            px = Mk[0] * a + Mk[1] * bq + Mk[2]  * cq + Mk[3];
            py = Mk[4] * a + Mk[5] * bq + Mk[6]  * cq + Mk[7];
            pz = Mk[8] * a + Mk[9] * bq + Mk[10] * cq + Mk[11];
        }
        mn[0] = px; mn[1] = py; mn[2] = pz;
        mx[0] = px; mx[1] = py; mx[2] = pz;
    }
    __shared__ float rmn[4][3], rmx[4][3];
    int lane = threadIdx.x & 63, wid = threadIdx.x >> 6;
#pragma unroll
    for (int i = 0; i < 3; i++) {
        float v = mn[i];
        for (int off = 32; off > 0; off >>= 1) v = fminf(v, __shfl_down(v, off, 64));
        if (lane == 0) rmn[wid][i] = v;
        float u = mx[i];
        for (int off = 32; off > 0; off >>= 1) u = fmaxf(u, __shfl_down(u, off, 64));
        if (lane == 0) rmx[wid][i] = u;
    }
    __syncthreads();
    unsigned* keys = (unsigned*)(ws + 256);
    if (threadIdx.x < 3) {
        int i = threadIdx.x;
        float v = fminf(fminf(rmn[0][i], rmn[1][i]), fminf(rmn[2][i], rmn[3][i]));
        atomicMin(&keys[b * 6 + i], fkey(v));
    } else if (threadIdx.x < 6) {
        int i = threadIdx.x - 3;
        float v = fmaxf(fmaxf(rmx[0][i], rmx[1][i]), fmaxf(rmx[2][i], rmx[3][i]));
        atomicMax(&keys[b * 6 + 3 + i], fkey(v));
    }
}

__global__ void k_prep(float* __restrict__ ws) {
    int b = threadIdx.x;
    if (b < NB) {
        const unsigned* keys = (const unsigned*)(ws + 256);
        float l0 = funkey(keys[b * 6 + 0]), l1 = funkey(keys[b * 6 + 1]), l2 = funkey(keys[b * 6 + 2]);
        float u0 = funkey(keys[b * 6 + 3]), u1 = funkey(keys[b * 6 + 4]), u2 = funkey(keys[b * 6 + 5]);
        float scale = fmaxf(u0 - l0, fmaxf(u1 - l1, u2 - l2));
        float safe = (scale == 0.f) ? 1.f : scale;
        bool flag = scale != 0.f;
        float* pr = ws + 288 + b * 8;
        pr[0] = l0; pr[1] = l1; pr[2] = l2; pr[3] = safe;
        pr[4] = flag ? 1.f : 0.f;
        // precompute the shared voxel for amax==0 masked pixels (pn = 0)
        float q0 = flag ? (0.f - l0) / safe : 0.f;
        float q1 = flag ? (0.f - l1) / safe : 0.f;
        float q2 = flag ? (0.f - l2) / safe : 0.f;
        int fl0 = vox1(q0) * 1024 + vox1(q1) * 32 + vox1(q2);
        ((int*)pr)[5] = fl0;
    }
}

// grid (75, 11, NB): gy handles channels [gy*8, gy*8+8) for 1024 pixels.
__global__ __launch_bounds__(256) void k_main(const f4* __restrict__ in4,
                                              f4* __restrict__ out4,
                                              float* __restrict__ occ,
                                              const float* __restrict__ ws) {
    const int b = blockIdx.z;
    const int gy = blockIdx.y;
    const int c0 = gy * 8;
    const int t = blockIdx.x * 256 + threadIdx.x;
    const size_t ib = (size_t)b * NCH * HW4 + t;
    const size_t ob = (size_t)b * OCH * HW4 + t;

    if (gy < 2) {   // channels 0..15: pure copy
        f4 v[8];
#pragma unroll
        for (int i = 0; i < 8; i++)
            v[i] = __builtin_nontemporal_load(&in4[ib + (size_t)(c0 + i) * HW4]);
#pragma unroll
        for (int i = 0; i < 8; i++)
            __builtin_nontemporal_store(v[i], &out4[ob + (size_t)(c0 + i) * HW4]);
        return;
    }

    __shared__ float accz[8];
    if (threadIdx.x < 8) accz[threadIdx.x] = 0.f;

    const float* Mb = ws + 64 + b * 36;
    const float* pr = ws + 288 + b * 8;
    float l0 = pr[0], l1 = pr[1], l2 = pr[2], safe = pr[3];
    bool flag = pr[4] != 0.f;
    int fl0 = ((const int*)pr)[5];

    // overhead channels (hot in L2/L3 — reused by all feat groups)
    f4 n0 = in4[ib];
    f4 n1 = in4[ib + HW4];
    f4 n2 = in4[ib + 2 * HW4];
    f4 mv = in4[ib + 3 * HW4];
    f4 g0 = in4[ib + 16 * HW4];
    f4 g1 = in4[ib + 17 * HW4];
    f4 g2 = in4[ib + 18 * HW4];
    f4 g3 = in4[ib + 19 * HW4];

    int flat[4]; bool spec[4], glb[4];
    f4 o0, o1, o2;
#pragma unroll
    for (int k = 0; k < 4; k++) {
        float m = sigmoidf_(mv[k]);
        bool masked = m > THRESHF;
        float v0 = g0[k], v1 = g1[k], v2 = g2[k], v3 = g3[k];
        int am = 0; float bb = v0;
        if (v1 > bb) { bb = v1; am = 1; }
        if (v2 > bb) { bb = v2; am = 2; }
        if (v3 > bb) { bb = v3; am = 3; }
        float px = 0.f, py = 0.f, pz = 0.f;
        if (am > 0) {
            const float* Mk = Mb + (am - 1) * 12;
            float a = n0[k], bq = n1[k], cq = n2[k];
            px = Mk[0] * a + Mk[1] * bq + Mk[2]  * cq + Mk[3];
            py = Mk[4] * a + Mk[5] * bq + Mk[6]  * cq + Mk[7];
            pz = Mk[8] * a + Mk[9] * bq + Mk[10] * cq + Mk[11];
        }
        float qx, qy, qz;
        if (flag) { qx = (px - l0) / safe; qy = (py - l1) / safe; qz = (pz - l2) / safe; }
        else      { qx = px; qy = py; qz = pz; }
        float ox = masked ? qx : 0.f, oy = masked ? qy : 0.f, oz = masked ? qz : 0.f;
        o0[k] = ox; o1[k] = oy; o2[k] = oz;
        spec[k] = masked && (am == 0);
        glb[k]  = masked && (am != 0);
        flat[k] = masked ? (vox1(ox) * 1024 + vox1(oy) * 32 + vox1(oz)) : 0;
    }

    if (gy == 2) {  // one group owns the pn_map channel writes
        __builtin_nontemporal_store(o0, &out4[ob + (size_t)86 * HW4]);
        __builtin_nontemporal_store(o1, &out4[ob + (size_t)87 * HW4]);
        __builtin_nontemporal_store(o2, &out4[ob + (size_t)88 * HW4]);
    }

    bool anySpec = spec[0] | spec[1] | spec[2] | spec[3];
    bool anyGlob = glb[0] | glb[1] | glb[2] | glb[3];
    float* occb = occ + ((size_t)(b * 64) << 15);

    __syncthreads();   // accz initialized

    f4 v[8];
#pragma unroll
    for (int i = 0; i < 8; i++) {
        int c = c0 + i;
        if (c < NCH) v[i] = __builtin_nontemporal_load(&in4[ib + (size_t)c * HW4]);
    }
#pragma unroll
    for (int i = 0; i < 8; i++) {
        int c = c0 + i;
        if (c >= NCH) continue;
        __builtin_nontemporal_store(v[i], &out4[ob + (size_t)c * HW4]);
        if (c >= 22) {
            int f = c - 22;
            if (anySpec) {
                float sv = 0.f;
#pragma unroll
                for (int k = 0; k < 4; k++) if (spec[k]) sv += v[i][k];
                if (sv != 0.f) atomicAdd(&accz[i], sv);
            }
            if (anyGlob) {
                float* of = occb + ((size_t)f << 15);
#pragma unroll
                for (int k = 0; k < 4; k++) if (glb[k]) atomicAdd(&of[flat[k]], v[i][k]);
            }
        }
    }
    __syncthreads();
    if (threadIdx.x < 8) {
        int c = c0 + threadIdx.x;
        float sv = accz[threadIdx.x];
        if (c >= 22 && c < NCH && sv != 0.f)
            atomicAdd(&occb[((size_t)(c - 22) << 15) + fl0], sv);
    }
}

extern "C" void kernel_launch(void* const* d_in, const int* in_sizes, int n_in,
                              void* d_out, int out_size, void* d_ws, size_t ws_size,
                              hipStream_t stream) {
    const float* in = (const float*)d_in[0];
    float* out = (float*)d_out;
    float* ws = (float*)d_ws;
    float* occ = out + (size_t)NB * OCH * HW;   // 27,340,800

    hipMemsetAsync(ws, 0, 64 * sizeof(float), stream);
    hipMemsetAsync(occ, 0, (size_t)NB * 64 * 32768 * sizeof(float), stream);

    dim3 gv(300, NB);
    k_votes <<<gv, 256, 0, stream>>>(in, ws);
    k_build <<<1, 64, 0, stream>>>(ws);
    k_minmax<<<gv, 256, 0, stream>>>(in, ws);
    k_prep  <<<1, 64, 0, stream>>>(ws);
    dim3 gm(75, 11, NB);
    k_main  <<<gm, 256, 0, stream>>>((const f4*)in, (f4*)out, occ, ws);
}

// Round 3
// 186.880 us; speedup vs baseline: 1.2046x; 1.2046x over previous
//
#include <hip/hip_runtime.h>
#include <math.h>

#define HW     76800
#define HW4    19200
#define NCH    86
#define OCH    89
#define NB     4
#define VOX    32768
#define THRESHF 0.7f
#define BIGF   1e30f

typedef float f4 __attribute__((ext_vector_type(4)));

// ws float layout:
// [0..63]    votes: b*16 + j*7 + {0:denom, 1..3:loc, 4..6:rot}
// [64..207]  M:     (b*3 + k)*12 row-major 3x4 [R|t]
// [256..279] minmax keys (uint32): b*6 + c   (0..2 low, 3..5 up)
// [288..319] prep:  b*8 + {0..2 low, 3 safe, 4 flag, 5 fl0(int bits)}
// [1024..]   occ_tmp: [b][vox][64] voxel-major scratch (33.5 MB)

__device__ __forceinline__ float sigmoidf_(float x) {
    if (x >= 0.f) { return 1.f / (1.f + expf(-x)); }
    float e = expf(x); return e / (1.f + e);
}
__device__ __forceinline__ unsigned fkey(float f) {
    unsigned u = __float_as_uint(f);
    return (u & 0x80000000u) ? ~u : (u | 0x80000000u);
}
__device__ __forceinline__ float funkey(unsigned k) {
    unsigned u = (k & 0x80000000u) ? (k ^ 0x80000000u) : ~k;
    return __uint_as_float(u);
}
__device__ __forceinline__ int vox1(float q) {
    int v = (int)floorf(q * 32.f);
    return v < 0 ? 0 : (v > 31 ? 31 : v);
}

__global__ __launch_bounds__(256) void k_votes(const float* __restrict__ in,
                                               float* __restrict__ ws) {
    const int b = blockIdx.y;
    const int p = blockIdx.x * 256 + threadIdx.x;
    const float* ib = in + (size_t)b * NCH * HW + p;
    float m  = sigmoidf_(ib[(size_t)3 * HW]);
    float s0 = sigmoidf_(ib[(size_t)20 * HW]) * m;
    float s1 = sigmoidf_(ib[(size_t)21 * HW]) * m;
    float w0 = m * s0, w1 = m * s1;
    float acc[14];
    acc[0] = s0; acc[7] = s1;
#pragma unroll
    for (int c = 0; c < 3; c++) {
        acc[1 + c]  = ib[(size_t)(4 + c)  * HW] * w0;
        acc[8 + c]  = ib[(size_t)(7 + c)  * HW] * w1;
        acc[4 + c]  = ib[(size_t)(10 + c) * HW] * w0;
        acc[11 + c] = ib[(size_t)(13 + c) * HW] * w1;
    }
    __shared__ float red[4][14];
    int lane = threadIdx.x & 63, wid = threadIdx.x >> 6;
#pragma unroll
    for (int i = 0; i < 14; i++) {
        float v = acc[i];
        for (int off = 32; off > 0; off >>= 1) v += __shfl_down(v, off, 64);
        if (lane == 0) red[wid][i] = v;
    }
    __syncthreads();
    if (threadIdx.x < 14) {
        float s = red[0][threadIdx.x] + red[1][threadIdx.x] +
                  red[2][threadIdx.x] + red[3][threadIdx.x];
        atomicAdd(&ws[b * 16 + threadIdx.x], s);
    }
}

__global__ void k_build(float* __restrict__ ws) {
    int tid = threadIdx.x;
    if (tid < 12) {
        int b = tid / 3, k = tid % 3;
        float lp0 = 0, lp1 = 0, lp2 = 0, rp0 = 0, rp1 = 0, rp2 = 0;
        if (k > 0) {
            const float* v = ws + b * 16 + (k - 1) * 7;
            float d = v[0] + 1e-5f;
            lp0 = v[1] / d; lp1 = v[2] / d; lp2 = v[3] / d;
            rp0 = v[4] / d; rp1 = v[5] / d; rp2 = v[6] / d;
        }
        float rx = -rp0, ry = -rp1, rz = -rp2;
        float ang = sqrtf(rx * rx + ry * ry + rz * rz) + 1e-8f;
        float ax = rx / ang, ay = ry / ang, az = rz / ang;
        float K[3][3] = {{0.f, -az, ay}, {az, 0.f, -ax}, {-ay, ax, 0.f}};
        float c = cosf(ang), s = sinf(ang);
        float K2[3][3], Rm[3][3];
#pragma unroll
        for (int i = 0; i < 3; i++)
#pragma unroll
            for (int j = 0; j < 3; j++)
                K2[i][j] = K[i][0] * K[0][j] + K[i][1] * K[1][j] + K[i][2] * K[2][j];
#pragma unroll
        for (int i = 0; i < 3; i++)
#pragma unroll
            for (int j = 0; j < 3; j++)
                Rm[i][j] = (i == j ? 1.f : 0.f) + s * K[i][j] + (1.f - c) * K2[i][j];
        float t0 = lp0, t1 = lp1, t2 = lp2;
        float* M = ws + 64 + (b * 3 + k) * 12;
#pragma unroll
        for (int i = 0; i < 3; i++) {
            M[i * 4 + 0] = Rm[i][0]; M[i * 4 + 1] = Rm[i][1]; M[i * 4 + 2] = Rm[i][2];
            float tt = (i == 0 ? t0 : (i == 1 ? t1 : t2));
            M[i * 4 + 3] = tt - (Rm[i][0] * t0 + Rm[i][1] * t1 + Rm[i][2] * t2);
        }
    }
    if (tid >= 12 && tid < 36) {
        int s2 = tid - 12;
        unsigned* keys = (unsigned*)(ws + 256);
        keys[s2] = ((s2 % 6) < 3) ? fkey(BIGF) : fkey(-BIGF);
    }
}

__global__ __launch_bounds__(256) void k_minmax(const float* __restrict__ in,
                                                float* __restrict__ ws) {
    const int b = blockIdx.y;
    const int p = blockIdx.x * 256 + threadIdx.x;
    const float* ib = in + (size_t)b * NCH * HW + p;
    const float* Mb = ws + 64 + b * 36;
    float mn[3] = {BIGF, BIGF, BIGF}, mx[3] = {-BIGF, -BIGF, -BIGF};
    float m = sigmoidf_(ib[(size_t)3 * HW]);
    if (m > THRESHF) {
        float v0 = ib[(size_t)16 * HW], v1 = ib[(size_t)17 * HW];
        float v2 = ib[(size_t)18 * HW], v3 = ib[(size_t)19 * HW];
        int am = 0; float bb = v0;
        if (v1 > bb) { bb = v1; am = 1; }
        if (v2 > bb) { bb = v2; am = 2; }
        if (v3 > bb) { bb = v3; am = 3; }
        float px = 0.f, py = 0.f, pz = 0.f;
        if (am > 0) {
            const float* Mk = Mb + (am - 1) * 12;
            float a = ib[0], bq = ib[(size_t)HW], cq = ib[(size_t)2 * HW];
            px = Mk[0] * a + Mk[1] * bq + Mk[2]  * cq + Mk[3];
            py = Mk[4] * a + Mk[5] * bq + Mk[6]  * cq + Mk[7];
            pz = Mk[8] * a + Mk[9] * bq + Mk[10] * cq + Mk[11];
        }
        mn[0] = px; mn[1] = py; mn[2] = pz;
        mx[0] = px; mx[1] = py; mx[2] = pz;
    }
    __shared__ float rmn[4][3], rmx[4][3];
    int lane = threadIdx.x & 63, wid = threadIdx.x >> 6;
#pragma unroll
    for (int i = 0; i < 3; i++) {
        float v = mn[i];
        for (int off = 32; off > 0; off >>= 1) v = fminf(v, __shfl_down(v, off, 64));
        if (lane == 0) rmn[wid][i] = v;
        float u = mx[i];
        for (int off = 32; off > 0; off >>= 1) u = fmaxf(u, __shfl_down(u, off, 64));
        if (lane == 0) rmx[wid][i] = u;
    }
    __syncthreads();
    unsigned* keys = (unsigned*)(ws + 256);
    if (threadIdx.x < 3) {
        int i = threadIdx.x;
        float v = fminf(fminf(rmn[0][i], rmn[1][i]), fminf(rmn[2][i], rmn[3][i]));
        atomicMin(&keys[b * 6 + i], fkey(v));
    } else if (threadIdx.x < 6) {
        int i = threadIdx.x - 3;
        float v = fmaxf(fmaxf(rmx[0][i], rmx[1][i]), fmaxf(rmx[2][i], rmx[3][i]));
        atomicMax(&keys[b * 6 + 3 + i], fkey(v));
    }
}

__global__ void k_prep(float* __restrict__ ws) {
    int b = threadIdx.x;
    if (b < NB) {
        const unsigned* keys = (const unsigned*)(ws + 256);
        float l0 = funkey(keys[b * 6 + 0]), l1 = funkey(keys[b * 6 + 1]), l2 = funkey(keys[b * 6 + 2]);
        float u0 = funkey(keys[b * 6 + 3]), u1 = funkey(keys[b * 6 + 4]), u2 = funkey(keys[b * 6 + 5]);
        float scale = fmaxf(u0 - l0, fmaxf(u1 - l1, u2 - l2));
        float safe = (scale == 0.f) ? 1.f : scale;
        bool flag = scale != 0.f;
        float* pr = ws + 288 + b * 8;
        pr[0] = l0; pr[1] = l1; pr[2] = l2; pr[3] = safe;
        pr[4] = flag ? 1.f : 0.f;
        float q0 = flag ? (0.f - l0) / safe : 0.f;
        float q1 = flag ? (0.f - l1) / safe : 0.f;
        float q2 = flag ? (0.f - l2) / safe : 0.f;
        int fl0 = vox1(q0) * 1024 + vox1(q1) * 32 + vox1(q2);
        ((int*)pr)[5] = fl0;
    }
}

// Scatter: block = 256 pixels. LDS transpose of 64 feat channels, then
// wave-per-pixel atomics with lane = channel.
// VOXMAJOR: dst = tmp[b][vox][64] (4 lines per pixel). else dst = occ[b][f][vox].
template<bool VOXMAJOR>
__global__ __launch_bounds__(256) void k_scatter(const float* __restrict__ in,
                                                 float* __restrict__ dst,
                                                 const float* __restrict__ ws) {
    __shared__ float tile[64][257];
    __shared__ float accz[4][64];
    const int b = blockIdx.y;
    const int tid = threadIdx.x;
    const int p = blockIdx.x * 256 + tid;
    const int lane = tid & 63, w = tid >> 6;
    const float* ib = in + (size_t)b * NCH * HW + p;
    const float* Mb = ws + 64 + b * 36;
    const float* pr = ws + 288 + b * 8;
    const float l0 = pr[0], l1 = pr[1], l2 = pr[2], safe = pr[3];
    const bool flag = pr[4] != 0.f;
    const int fl0 = ((const int*)pr)[5];

    float m = sigmoidf_(ib[(size_t)3 * HW]);
    bool masked = m > THRESHF;
    int am = 0;
    {
        float v0 = ib[(size_t)16 * HW], v1 = ib[(size_t)17 * HW];
        float v2 = ib[(size_t)18 * HW], v3 = ib[(size_t)19 * HW];
        float bb = v0;
        if (v1 > bb) { bb = v1; am = 1; }
        if (v2 > bb) { bb = v2; am = 2; }
        if (v3 > bb) { bb = v3; am = 3; }
    }
    bool glb  = masked && (am != 0);
    bool spec = masked && (am == 0);
    int flat = fl0;
    if (glb) {
        const float* Mk = Mb + (am - 1) * 12;
        float a = ib[0], bq = ib[(size_t)HW], cq = ib[(size_t)2 * HW];
        float px = Mk[0] * a + Mk[1] * bq + Mk[2]  * cq + Mk[3];
        float py = Mk[4] * a + Mk[5] * bq + Mk[6]  * cq + Mk[7];
        float pz = Mk[8] * a + Mk[9] * bq + Mk[10] * cq + Mk[11];
        float qx, qy, qz;
        if (flag) { qx = (px - l0) / safe; qy = (py - l1) / safe; qz = (pz - l2) / safe; }
        else      { qx = px; qy = py; qz = pz; }
        flat = vox1(qx) * 1024 + vox1(qy) * 32 + vox1(qz);
    }

#pragma unroll 8
    for (int c = 0; c < 64; c++)
        tile[c][tid] = ib[(size_t)(22 + c) * HW];

    unsigned long long gm = __ballot(glb);
    unsigned long long sm = __ballot(spec);
    __syncthreads();

    while (gm) {
        int i = __ffsll((unsigned long long)gm) - 1; gm &= gm - 1;
        int fl = __shfl(flat, i, 64);
        float v = tile[lane][w * 64 + i];
        if (VOXMAJOR)
            atomicAdd(&dst[(((size_t)b * VOX + fl) << 6) + lane], v);
        else
            atomicAdd(&dst[(((size_t)(b * 64 + lane)) << 15) + fl], v);
    }
    float sacc = 0.f;
    while (sm) {
        int i = __ffsll((unsigned long long)sm) - 1; sm &= sm - 1;
        sacc += tile[lane][w * 64 + i];
    }
    accz[w][lane] = sacc;
    __syncthreads();
    if (tid < 64) {
        float s = accz[0][tid] + accz[1][tid] + accz[2][tid] + accz[3][tid];
        if (s != 0.f) {
            if (VOXMAJOR)
                atomicAdd(&dst[(((size_t)b * VOX + fl0) << 6) + tid], s);
            else
                atomicAdd(&dst[(((size_t)(b * 64 + tid)) << 15) + fl0], s);
        }
    }
}

// Pure streaming copy + pn_map channels (no atomics).
__global__ __launch_bounds__(256) void k_copy(const f4* __restrict__ in4,
                                              f4* __restrict__ out4,
                                              const float* __restrict__ ws) {
    const int b = blockIdx.z;
    const int gy = blockIdx.y;
    const int t = blockIdx.x * 256 + threadIdx.x;
    const size_t ib = (size_t)b * NCH * HW4 + t;
    const size_t ob = (size_t)b * OCH * HW4 + t;

    if (gy < 10) {
        const int c0 = gy * 8;
        f4 v[8];
#pragma unroll
        for (int i = 0; i < 8; i++) v[i] = in4[ib + (size_t)(c0 + i) * HW4];
#pragma unroll
        for (int i = 0; i < 8; i++)
            __builtin_nontemporal_store(v[i], &out4[ob + (size_t)(c0 + i) * HW4]);
        return;
    }
    // gy == 10: channels 80..85 + pn_map 86..88
    f4 v[6];
#pragma unroll
    for (int i = 0; i < 6; i++) v[i] = in4[ib + (size_t)(80 + i) * HW4];
#pragma unroll
    for (int i = 0; i < 6; i++)
        __builtin_nontemporal_store(v[i], &out4[ob + (size_t)(80 + i) * HW4]);

    const float* Mb = ws + 64 + b * 36;
    const float* pr = ws + 288 + b * 8;
    float l0 = pr[0], l1 = pr[1], l2 = pr[2], safe = pr[3];
    bool flag = pr[4] != 0.f;
    f4 n0 = in4[ib];
    f4 n1 = in4[ib + HW4];
    f4 n2 = in4[ib + 2 * HW4];
    f4 mv = in4[ib + 3 * HW4];
    f4 g0 = in4[ib + 16 * HW4];
    f4 g1 = in4[ib + 17 * HW4];
    f4 g2 = in4[ib + 18 * HW4];
    f4 g3 = in4[ib + 19 * HW4];
    f4 o0, o1, o2;
#pragma unroll
    for (int k = 0; k < 4; k++) {
        float m = sigmoidf_(mv[k]);
        bool masked = m > THRESHF;
        float v0 = g0[k], v1 = g1[k], v2 = g2[k], v3 = g3[k];
        int am = 0; float bb = v0;
        if (v1 > bb) { bb = v1; am = 1; }
        if (v2 > bb) { bb = v2; am = 2; }
        if (v3 > bb) { bb = v3; am = 3; }
        float px = 0.f, py = 0.f, pz = 0.f;
        if (am > 0) {
            const float* Mk = Mb + (am - 1) * 12;
            float a = n0[k], bq = n1[k], cq = n2[k];
            px = Mk[0] * a + Mk[1] * bq + Mk[2]  * cq + Mk[3];
            py = Mk[4] * a + Mk[5] * bq + Mk[6]  * cq + Mk[7];
            pz = Mk[8] * a + Mk[9] * bq + Mk[10] * cq + Mk[11];
        }
        float qx, qy, qz;
        if (flag) { qx = (px - l0) / safe; qy = (py - l1) / safe; qz = (pz - l2) / safe; }
        else      { qx = px; qy = py; qz = pz; }
        o0[k] = masked ? qx : 0.f;
        o1[k] = masked ? qy : 0.f;
        o2[k] = masked ? qz : 0.f;
    }
    __builtin_nontemporal_store(o0, &out4[ob + (size_t)86 * HW4]);
    __builtin_nontemporal_store(o1, &out4[ob + (size_t)87 * HW4]);
    __builtin_nontemporal_store(o2, &out4[ob + (size_t)88 * HW4]);
}

// tmp[b][vox][64] -> occ[b][64][vox], 64-voxel tiles via LDS.
__global__ __launch_bounds__(256) void k_transpose(const float* __restrict__ tmp,
                                                   float* __restrict__ occ) {
    __shared__ float ld[64][65];
    const int b = blockIdx.y;
    const int vox0 = blockIdx.x * 64;
    const int t = threadIdx.x;
    const int v = t & 63, g = t >> 6;          // g in 0..3: 16 channels each
    const float* src = tmp + (((size_t)b * VOX + vox0 + v) << 6) + g * 16;
#pragma unroll
    for (int i = 0; i < 4; i++) {
        f4 x = *(const f4*)(src + 4 * i);
        ld[g * 16 + 4 * i + 0][v] = x[0];
        ld[g * 16 + 4 * i + 1][v] = x[1];
        ld[g * 16 + 4 * i + 2][v] = x[2];
        ld[g * 16 + 4 * i + 3][v] = x[3];
    }
    __syncthreads();
    const int f = t >> 2;                       // 4 threads per channel
    float* dstp = occ + (((size_t)(b * 64 + f)) << 15) + vox0;
#pragma unroll
    for (int i = 0; i < 4; i++) {
        int mq = (t & 3) * 4 + i;               // f4 index 0..15
        f4 x;
        x[0] = ld[f][4 * mq + 0]; x[1] = ld[f][4 * mq + 1];
        x[2] = ld[f][4 * mq + 2]; x[3] = ld[f][4 * mq + 3];
        __builtin_nontemporal_store(x, (f4*)(dstp + 4 * mq));
    }
}

extern "C" void kernel_launch(void* const* d_in, const int* in_sizes, int n_in,
                              void* d_out, int out_size, void* d_ws, size_t ws_size,
                              hipStream_t stream) {
    const float* in = (const float*)d_in[0];
    float* out = (float*)d_out;
    float* ws = (float*)d_ws;
    float* occ = out + (size_t)NB * OCH * HW;
    float* tmp = ws + 1024;
    const size_t tmp_bytes = (size_t)NB * VOX * 64 * sizeof(float);
    const bool voxmajor = ws_size >= 4096 + tmp_bytes;

    hipMemsetAsync(ws, 0, 64 * sizeof(float), stream);
    if (voxmajor) hipMemsetAsync(tmp, 0, tmp_bytes, stream);
    else          hipMemsetAsync(occ, 0, tmp_bytes, stream);

    dim3 gv(300, NB);
    k_votes <<<gv, 256, 0, stream>>>(in, ws);
    k_build <<<1, 64, 0, stream>>>(ws);
    k_minmax<<<gv, 256, 0, stream>>>(in, ws);
    k_prep  <<<1, 64, 0, stream>>>(ws);
    if (voxmajor) k_scatter<true> <<<gv, 256, 0, stream>>>(in, tmp, ws);
    else          k_scatter<false><<<gv, 256, 0, stream>>>(in, occ, ws);
    dim3 gc(75, 11, NB);
    k_copy  <<<gc, 256, 0, stream>>>((const f4*)in, (f4*)out, ws);
    if (voxmajor) {
        dim3 gt(VOX / 64, NB);
        k_transpose<<<gt, 256, 0, stream>>>(tmp, occ);
    }
}

// Round 4
// 180.354 us; speedup vs baseline: 1.2482x; 1.0362x over previous
//
#include <hip/hip_runtime.h>
#include <math.h>

#define HW     76800
#define HW4    19200
#define NCH    86
#define OCH    89
#define NB     4
#define VOX    32768
#define THRESHF 0.7f
#define BIGF   1e30f

typedef float f4 __attribute__((ext_vector_type(4)));

// ws float layout:
// [0..63]    votes: b*16 + j*7 + {0:denom, 1..3:loc, 4..6:rot}
// [64..207]  M:     (b*3 + k)*12 row-major 3x4 [R|t]
// [256..279] minmax keys (uint32): b*6 + c   (0..2 low, 3..5 up)
// [288..319] prep:  b*8 + {0..2 low, 3 safe, 4 flag, 5 fl0(int bits)}
// [1024..]   occ_tmp: [b][vox][64] voxel-major scratch (33.5 MB)

__device__ __forceinline__ float sigmoidf_(float x) {
    if (x >= 0.f) { return 1.f / (1.f + expf(-x)); }
    float e = expf(x); return e / (1.f + e);
}
__device__ __forceinline__ unsigned fkey(float f) {
    unsigned u = __float_as_uint(f);
    return (u & 0x80000000u) ? ~u : (u | 0x80000000u);
}
__device__ __forceinline__ float funkey(unsigned k) {
    unsigned u = (k & 0x80000000u) ? (k ^ 0x80000000u) : ~k;
    return __uint_as_float(u);
}
__device__ __forceinline__ int vox1(float q) {
    int v = (int)floorf(q * 32.f);
    return v < 0 ? 0 : (v > 31 ? 31 : v);
}

// Custom zero: rocclr fillBuffer ran at 417 GB/s (80 µs) in-graph; this
// grid-stride f4 kernel does the same 33.5 MB in ~6 µs. Also zeroes the
// 64-float vote slab (needed before k_votes' atomics).
__global__ __launch_bounds__(256) void k_zero(f4* __restrict__ p, unsigned n4,
                                              float* __restrict__ ws) {
    unsigned i = blockIdx.x * 256 + threadIdx.x;
    const unsigned stride = gridDim.x * 256;
    f4 z = {0.f, 0.f, 0.f, 0.f};
    for (; i < n4; i += stride) __builtin_nontemporal_store(z, &p[i]);
    if (blockIdx.x == 0 && threadIdx.x < 64) ws[threadIdx.x] = 0.f;
}

__global__ __launch_bounds__(256) void k_votes(const float* __restrict__ in,
                                               float* __restrict__ ws) {
    const int b = blockIdx.y;
    const int p = blockIdx.x * 256 + threadIdx.x;
    const float* ib = in + (size_t)b * NCH * HW + p;
    float m  = sigmoidf_(ib[(size_t)3 * HW]);
    float s0 = sigmoidf_(ib[(size_t)20 * HW]) * m;
    float s1 = sigmoidf_(ib[(size_t)21 * HW]) * m;
    float w0 = m * s0, w1 = m * s1;
    float acc[14];
    acc[0] = s0; acc[7] = s1;
#pragma unroll
    for (int c = 0; c < 3; c++) {
        acc[1 + c]  = ib[(size_t)(4 + c)  * HW] * w0;
        acc[8 + c]  = ib[(size_t)(7 + c)  * HW] * w1;
        acc[4 + c]  = ib[(size_t)(10 + c) * HW] * w0;
        acc[11 + c] = ib[(size_t)(13 + c) * HW] * w1;
    }
    __shared__ float red[4][14];
    int lane = threadIdx.x & 63, wid = threadIdx.x >> 6;
#pragma unroll
    for (int i = 0; i < 14; i++) {
        float v = acc[i];
        for (int off = 32; off > 0; off >>= 1) v += __shfl_down(v, off, 64);
        if (lane == 0) red[wid][i] = v;
    }
    __syncthreads();
    if (threadIdx.x < 14) {
        float s = red[0][threadIdx.x] + red[1][threadIdx.x] +
                  red[2][threadIdx.x] + red[3][threadIdx.x];
        atomicAdd(&ws[b * 16 + threadIdx.x], s);
    }
}

__global__ void k_build(float* __restrict__ ws) {
    int tid = threadIdx.x;
    if (tid < 12) {
        int b = tid / 3, k = tid % 3;
        float lp0 = 0, lp1 = 0, lp2 = 0, rp0 = 0, rp1 = 0, rp2 = 0;
        if (k > 0) {
            const float* v = ws + b * 16 + (k - 1) * 7;
            float d = v[0] + 1e-5f;
            lp0 = v[1] / d; lp1 = v[2] / d; lp2 = v[3] / d;
            rp0 = v[4] / d; rp1 = v[5] / d; rp2 = v[6] / d;
        }
        float rx = -rp0, ry = -rp1, rz = -rp2;
        float ang = sqrtf(rx * rx + ry * ry + rz * rz) + 1e-8f;
        float ax = rx / ang, ay = ry / ang, az = rz / ang;
        float K[3][3] = {{0.f, -az, ay}, {az, 0.f, -ax}, {-ay, ax, 0.f}};
        float c = cosf(ang), s = sinf(ang);
        float K2[3][3], Rm[3][3];
#pragma unroll
        for (int i = 0; i < 3; i++)
#pragma unroll
            for (int j = 0; j < 3; j++)
                K2[i][j] = K[i][0] * K[0][j] + K[i][1] * K[1][j] + K[i][2] * K[2][j];
#pragma unroll
        for (int i = 0; i < 3; i++)
#pragma unroll
            for (int j = 0; j < 3; j++)
                Rm[i][j] = (i == j ? 1.f : 0.f) + s * K[i][j] + (1.f - c) * K2[i][j];
        float t0 = lp0, t1 = lp1, t2 = lp2;
        float* M = ws + 64 + (b * 3 + k) * 12;
#pragma unroll
        for (int i = 0; i < 3; i++) {
            M[i * 4 + 0] = Rm[i][0]; M[i * 4 + 1] = Rm[i][1]; M[i * 4 + 2] = Rm[i][2];
            float tt = (i == 0 ? t0 : (i == 1 ? t1 : t2));
            M[i * 4 + 3] = tt - (Rm[i][0] * t0 + Rm[i][1] * t1 + Rm[i][2] * t2);
        }
    }
    if (tid >= 12 && tid < 36) {
        int s2 = tid - 12;
        unsigned* keys = (unsigned*)(ws + 256);
        keys[s2] = ((s2 % 6) < 3) ? fkey(BIGF) : fkey(-BIGF);
    }
}

__global__ __launch_bounds__(256) void k_minmax(const float* __restrict__ in,
                                                float* __restrict__ ws) {
    const int b = blockIdx.y;
    const int p = blockIdx.x * 256 + threadIdx.x;
    const float* ib = in + (size_t)b * NCH * HW + p;
    const float* Mb = ws + 64 + b * 36;
    float mn[3] = {BIGF, BIGF, BIGF}, mx[3] = {-BIGF, -BIGF, -BIGF};
    float m = sigmoidf_(ib[(size_t)3 * HW]);
    if (m > THRESHF) {
        float v0 = ib[(size_t)16 * HW], v1 = ib[(size_t)17 * HW];
        float v2 = ib[(size_t)18 * HW], v3 = ib[(size_t)19 * HW];
        int am = 0; float bb = v0;
        if (v1 > bb) { bb = v1; am = 1; }
        if (v2 > bb) { bb = v2; am = 2; }
        if (v3 > bb) { bb = v3; am = 3; }
        float px = 0.f, py = 0.f, pz = 0.f;
        if (am > 0) {
            const float* Mk = Mb + (am - 1) * 12;
            float a = ib[0], bq = ib[(size_t)HW], cq = ib[(size_t)2 * HW];
            px = Mk[0] * a + Mk[1] * bq + Mk[2]  * cq + Mk[3];
            py = Mk[4] * a + Mk[5] * bq + Mk[6]  * cq + Mk[7];
            pz = Mk[8] * a + Mk[9] * bq + Mk[10] * cq + Mk[11];
        }
        mn[0] = px; mn[1] = py; mn[2] = pz;
        mx[0] = px; mx[1] = py; mx[2] = pz;
    }
    __shared__ float rmn[4][3], rmx[4][3];
    int lane = threadIdx.x & 63, wid = threadIdx.x >> 6;
#pragma unroll
    for (int i = 0; i < 3; i++) {
        float v = mn[i];
        for (int off = 32; off > 0; off >>= 1) v = fminf(v, __shfl_down(v, off, 64));
        if (lane == 0) rmn[wid][i] = v;
        float u = mx[i];
        for (int off = 32; off > 0; off >>= 1) u = fmaxf(u, __shfl_down(u, off, 64));
        if (lane == 0) rmx[wid][i] = u;
    }
    __syncthreads();
    unsigned* keys = (unsigned*)(ws + 256);
    if (threadIdx.x < 3) {
        int i = threadIdx.x;
        float v = fminf(fminf(rmn[0][i], rmn[1][i]), fminf(rmn[2][i], rmn[3][i]));
        atomicMin(&keys[b * 6 + i], fkey(v));
    } else if (threadIdx.x < 6) {
        int i = threadIdx.x - 3;
        float v = fmaxf(fmaxf(rmx[0][i], rmx[1][i]), fmaxf(rmx[2][i], rmx[3][i]));
        atomicMax(&keys[b * 6 + 3 + i], fkey(v));
    }
}

__global__ void k_prep(float* __restrict__ ws) {
    int b = threadIdx.x;
    if (b < NB) {
        const unsigned* keys = (const unsigned*)(ws + 256);
        float l0 = funkey(keys[b * 6 + 0]), l1 = funkey(keys[b * 6 + 1]), l2 = funkey(keys[b * 6 + 2]);
        float u0 = funkey(keys[b * 6 + 3]), u1 = funkey(keys[b * 6 + 4]), u2 = funkey(keys[b * 6 + 5]);
        float scale = fmaxf(u0 - l0, fmaxf(u1 - l1, u2 - l2));
        float safe = (scale == 0.f) ? 1.f : scale;
        bool flag = scale != 0.f;
        float* pr = ws + 288 + b * 8;
        pr[0] = l0; pr[1] = l1; pr[2] = l2; pr[3] = safe;
        pr[4] = flag ? 1.f : 0.f;
        float q0 = flag ? (0.f - l0) / safe : 0.f;
        float q1 = flag ? (0.f - l1) / safe : 0.f;
        float q2 = flag ? (0.f - l2) / safe : 0.f;
        int fl0 = vox1(q0) * 1024 + vox1(q1) * 32 + vox1(q2);
        ((int*)pr)[5] = fl0;
    }
}

// Fused scatter + feat-channel copy (ch 22..85). Block = 256 pixels.
// LDS transpose of 64 feat channels; copy stores emitted during staging;
// wave-per-pixel atomics with lane = channel.
// VOXMAJOR: dst = tmp[b][vox][64] (4 lines per pixel). else dst = occ[b][f][vox].
template<bool VOXMAJOR>
__global__ __launch_bounds__(256) void k_scatter(const float* __restrict__ in,
                                                 float* __restrict__ out,
                                                 float* __restrict__ dst,
                                                 const float* __restrict__ ws) {
    __shared__ float tile[64][257];
    __shared__ float accz[4][64];
    const int b = blockIdx.y;
    const int tid = threadIdx.x;
    const int p = blockIdx.x * 256 + tid;
    const int lane = tid & 63, w = tid >> 6;
    const float* ib = in + (size_t)b * NCH * HW + p;
    float* ob = out + (size_t)b * OCH * HW + p;
    const float* Mb = ws + 64 + b * 36;
    const float* pr = ws + 288 + b * 8;
    const float l0 = pr[0], l1 = pr[1], l2 = pr[2], safe = pr[3];
    const bool flag = pr[4] != 0.f;
    const int fl0 = ((const int*)pr)[5];

    float m = sigmoidf_(ib[(size_t)3 * HW]);
    bool masked = m > THRESHF;
    int am = 0;
    {
        float v0 = ib[(size_t)16 * HW], v1 = ib[(size_t)17 * HW];
        float v2 = ib[(size_t)18 * HW], v3 = ib[(size_t)19 * HW];
        float bb = v0;
        if (v1 > bb) { bb = v1; am = 1; }
        if (v2 > bb) { bb = v2; am = 2; }
        if (v3 > bb) { bb = v3; am = 3; }
    }
    bool glb  = masked && (am != 0);
    bool spec = masked && (am == 0);
    int flat = fl0;
    if (glb) {
        const float* Mk = Mb + (am - 1) * 12;
        float a = ib[0], bq = ib[(size_t)HW], cq = ib[(size_t)2 * HW];
        float px = Mk[0] * a + Mk[1] * bq + Mk[2]  * cq + Mk[3];
        float py = Mk[4] * a + Mk[5] * bq + Mk[6]  * cq + Mk[7];
        float pz = Mk[8] * a + Mk[9] * bq + Mk[10] * cq + Mk[11];
        float qx, qy, qz;
        if (flag) { qx = (px - l0) / safe; qy = (py - l1) / safe; qz = (pz - l2) / safe; }
        else      { qx = px; qy = py; qz = pz; }
        flat = vox1(qx) * 1024 + vox1(qy) * 32 + vox1(qz);
    }

#pragma unroll 8
    for (int c = 0; c < 64; c++) {
        float v = __builtin_nontemporal_load(&ib[(size_t)(22 + c) * HW]);
        tile[c][tid] = v;
        __builtin_nontemporal_store(v, &ob[(size_t)(22 + c) * HW]);
    }

    unsigned long long gm = __ballot(glb);
    unsigned long long sm = __ballot(spec);
    __syncthreads();

    while (gm) {
        int i = __ffsll((unsigned long long)gm) - 1; gm &= gm - 1;
        int fl = __shfl(flat, i, 64);
        float v = tile[lane][w * 64 + i];
        if (VOXMAJOR)
            atomicAdd(&dst[(((size_t)b * VOX + fl) << 6) + lane], v);
        else
            atomicAdd(&dst[(((size_t)(b * 64 + lane)) << 15) + fl], v);
    }
    float sacc = 0.f;
    while (sm) {
        int i = __ffsll((unsigned long long)sm) - 1; sm &= sm - 1;
        sacc += tile[lane][w * 64 + i];
    }
    accz[w][lane] = sacc;
    __syncthreads();
    if (tid < 64) {
        float s = accz[0][tid] + accz[1][tid] + accz[2][tid] + accz[3][tid];
        if (s != 0.f) {
            if (VOXMAJOR)
                atomicAdd(&dst[(((size_t)b * VOX + fl0) << 6) + tid], s);
            else
                atomicAdd(&dst[(((size_t)(b * 64 + tid)) << 15) + fl0], s);
        }
    }
}

// Streaming copy of channels 0..21 + pn_map channels 86..88.
// grid (75, 3, NB): gy0 = ch0..7, gy1 = ch8..15, gy2 = ch16..21 + pn.
__global__ __launch_bounds__(256) void k_copy(const f4* __restrict__ in4,
                                              f4* __restrict__ out4,
                                              const float* __restrict__ ws) {
    const int b = blockIdx.z;
    const int gy = blockIdx.y;
    const int t = blockIdx.x * 256 + threadIdx.x;
    const size_t ib = (size_t)b * NCH * HW4 + t;
    const size_t ob = (size_t)b * OCH * HW4 + t;

    if (gy < 2) {
        const int c0 = gy * 8;
        f4 v[8];
#pragma unroll
        for (int i = 0; i < 8; i++) v[i] = in4[ib + (size_t)(c0 + i) * HW4];
#pragma unroll
        for (int i = 0; i < 8; i++)
            __builtin_nontemporal_store(v[i], &out4[ob + (size_t)(c0 + i) * HW4]);
        return;
    }
    // gy == 2: channels 16..21 + pn_map 86..88 (pn inputs: ch 0..3, 16..19)
    f4 g0 = in4[ib + 16 * HW4];
    f4 g1 = in4[ib + 17 * HW4];
    f4 g2 = in4[ib + 18 * HW4];
    f4 g3 = in4[ib + 19 * HW4];
    f4 c20 = in4[ib + 20 * HW4];
    f4 c21 = in4[ib + 21 * HW4];
    __builtin_nontemporal_store(g0,  &out4[ob + 16 * HW4]);
    __builtin_nontemporal_store(g1,  &out4[ob + 17 * HW4]);
    __builtin_nontemporal_store(g2,  &out4[ob + 18 * HW4]);
    __builtin_nontemporal_store(g3,  &out4[ob + 19 * HW4]);
    __builtin_nontemporal_store(c20, &out4[ob + 20 * HW4]);
    __builtin_nontemporal_store(c21, &out4[ob + 21 * HW4]);

    const float* Mb = ws + 64 + b * 36;
    const float* pr = ws + 288 + b * 8;
    float l0 = pr[0], l1 = pr[1], l2 = pr[2], safe = pr[3];
    bool flag = pr[4] != 0.f;
    f4 n0 = in4[ib];
    f4 n1 = in4[ib + HW4];
    f4 n2 = in4[ib + 2 * HW4];
    f4 mv = in4[ib + 3 * HW4];
    f4 o0, o1, o2;
#pragma unroll
    for (int k = 0; k < 4; k++) {
        float m = sigmoidf_(mv[k]);
        bool masked = m > THRESHF;
        float v0 = g0[k], v1 = g1[k], v2 = g2[k], v3 = g3[k];
        int am = 0; float bb = v0;
        if (v1 > bb) { bb = v1; am = 1; }
        if (v2 > bb) { bb = v2; am = 2; }
        if (v3 > bb) { bb = v3; am = 3; }
        float px = 0.f, py = 0.f, pz = 0.f;
        if (am > 0) {
            const float* Mk = Mb + (am - 1) * 12;
            float a = n0[k], bq = n1[k], cq = n2[k];
            px = Mk[0] * a + Mk[1] * bq + Mk[2]  * cq + Mk[3];
            py = Mk[4] * a + Mk[5] * bq + Mk[6]  * cq + Mk[7];
            pz = Mk[8] * a + Mk[9] * bq + Mk[10] * cq + Mk[11];
        }
        float qx, qy, qz;
        if (flag) { qx = (px - l0) / safe; qy = (py - l1) / safe; qz = (pz - l2) / safe; }
        else      { qx = px; qy = py; qz = pz; }
        o0[k] = masked ? qx : 0.f;
        o1[k] = masked ? qy : 0.f;
        o2[k] = masked ? qz : 0.f;
    }
    __builtin_nontemporal_store(o0, &out4[ob + (size_t)86 * HW4]);
    __builtin_nontemporal_store(o1, &out4[ob + (size_t)87 * HW4]);
    __builtin_nontemporal_store(o2, &out4[ob + (size_t)88 * HW4]);
}

// tmp[b][vox][64] -> occ[b][64][vox], 64-voxel tiles via LDS.
__global__ __launch_bounds__(256) void k_transpose(const float* __restrict__ tmp,
                                                   float* __restrict__ occ) {
    __shared__ float ld[64][65];
    const int b = blockIdx.y;
    const int vox0 = blockIdx.x * 64;
    const int t = threadIdx.x;
    const int v = t & 63, g = t >> 6;
    const float* src = tmp + (((size_t)b * VOX + vox0 + v) << 6) + g * 16;
#pragma unroll
    for (int i = 0; i < 4; i++) {
        f4 x = *(const f4*)(src + 4 * i);
        ld[g * 16 + 4 * i + 0][v] = x[0];
        ld[g * 16 + 4 * i + 1][v] = x[1];
        ld[g * 16 + 4 * i + 2][v] = x[2];
        ld[g * 16 + 4 * i + 3][v] = x[3];
    }
    __syncthreads();
    const int f = t >> 2;
    float* dstp = occ + (((size_t)(b * 64 + f)) << 15) + vox0;
#pragma unroll
    for (int i = 0; i < 4; i++) {
        int mq = (t & 3) * 4 + i;
        f4 x;
        x[0] = ld[f][4 * mq + 0]; x[1] = ld[f][4 * mq + 1];
        x[2] = ld[f][4 * mq + 2]; x[3] = ld[f][4 * mq + 3];
        __builtin_nontemporal_store(x, (f4*)(dstp + 4 * mq));
    }
}

extern "C" void kernel_launch(void* const* d_in, const int* in_sizes, int n_in,
                              void* d_out, int out_size, void* d_ws, size_t ws_size,
                              hipStream_t stream) {
    const float* in = (const float*)d_in[0];
    float* out = (float*)d_out;
    float* ws = (float*)d_ws;
    float* occ = out + (size_t)NB * OCH * HW;
    float* tmp = ws + 1024;
    const size_t tmp_bytes = (size_t)NB * VOX * 64 * sizeof(float);
    const bool voxmajor = ws_size >= 4096 + tmp_bytes;
    const unsigned n4 = (unsigned)(tmp_bytes / 16);

    if (voxmajor) k_zero<<<2048, 256, 0, stream>>>((f4*)tmp, n4, ws);
    else          k_zero<<<2048, 256, 0, stream>>>((f4*)occ, n4, ws);

    dim3 gv(300, NB);
    k_votes <<<gv, 256, 0, stream>>>(in, ws);
    k_build <<<1, 64, 0, stream>>>(ws);
    k_minmax<<<gv, 256, 0, stream>>>(in, ws);
    k_prep  <<<1, 64, 0, stream>>>(ws);
    if (voxmajor) k_scatter<true> <<<gv, 256, 0, stream>>>(in, out, tmp, ws);
    else          k_scatter<false><<<gv, 256, 0, stream>>>(in, out, occ, ws);
    dim3 gc(75, 3, NB);
    k_copy  <<<gc, 256, 0, stream>>>((const f4*)in, (f4*)out, ws);
    if (voxmajor) {
        dim3 gt(VOX / 64, NB);
        k_transpose<<<gt, 256, 0, stream>>>(tmp, occ);
    }
}

// Round 5
// 168.123 us; speedup vs baseline: 1.3390x; 1.0728x over previous
//
#include <hip/hip_runtime.h>
#include <math.h>

#define HW     76800
#define HW4    19200
#define NCH    86
#define OCH    89
#define NB     4
#define VOX    32768
#define NBLK   300        // pixel blocks per batch (256 px each)
#define THRESHF 0.7f
#define BIGF   1e30f

typedef float f4 __attribute__((ext_vector_type(4)));

// ws float layout:
// [64..207]   M: (b*3 + k)*12 row-major 3x4 [R|t]         (k_build)
// [256..279]  minmax keys (uint32): b*6 + c               (init k_build, k_minmax)
// [288..319]  prep: b*8 + {0..2 low, 3 safe, 4 flag, 5 fl0(int)}  (k_prep)
// [512..512+NB*NBLK*16)  vote partials: (b*NBLK+bx)*16+i, i<14    (k_votes_zero)
// [32768..]   occ_tmp: [b][vox][64] voxel-major scratch (33.5 MB)

__device__ __forceinline__ float sigmoidf_(float x) {
    if (x >= 0.f) { return 1.f / (1.f + expf(-x)); }
    float e = expf(x); return e / (1.f + e);
}
__device__ __forceinline__ unsigned fkey(float f) {
    unsigned u = __float_as_uint(f);
    return (u & 0x80000000u) ? ~u : (u | 0x80000000u);
}
__device__ __forceinline__ float funkey(unsigned k) {
    unsigned u = (k & 0x80000000u) ? (k ^ 0x80000000u) : ~k;
    return __uint_as_float(u);
}
__device__ __forceinline__ int vox1(float q) {
    int v = (int)floorf(q * 32.f);
    return v < 0 ? 0 : (v > 31 ? 31 : v);
}

// Fused: per-block vote partials (no atomics, no pre-zero needed) + grid-stride
// zeroing of the voxel-major scratch (replaces the slow rocclr fill).
__global__ __launch_bounds__(256) void k_votes_zero(const float* __restrict__ in,
                                                    float* __restrict__ ws,
                                                    f4* __restrict__ zp, unsigned n4) {
    const int b = blockIdx.y;
    const int bx = blockIdx.x;
    const int p = bx * 256 + threadIdx.x;

    // zero slice of tmp (stride = total threads)
    {
        unsigned gid = ((unsigned)(b * NBLK + bx)) * 256u + threadIdx.x;
        const unsigned stride = NB * NBLK * 256u;
        f4 z = {0.f, 0.f, 0.f, 0.f};
        for (unsigned i = gid; i < n4; i += stride)
            __builtin_nontemporal_store(z, &zp[i]);
    }

    const float* ib = in + (size_t)b * NCH * HW + p;
    float m  = sigmoidf_(ib[(size_t)3 * HW]);
    float s0 = sigmoidf_(ib[(size_t)20 * HW]) * m;
    float s1 = sigmoidf_(ib[(size_t)21 * HW]) * m;
    float w0 = m * s0, w1 = m * s1;
    float acc[14];
    acc[0] = s0; acc[7] = s1;
#pragma unroll
    for (int c = 0; c < 3; c++) {
        acc[1 + c]  = ib[(size_t)(4 + c)  * HW] * w0;
        acc[8 + c]  = ib[(size_t)(7 + c)  * HW] * w1;
        acc[4 + c]  = ib[(size_t)(10 + c) * HW] * w0;
        acc[11 + c] = ib[(size_t)(13 + c) * HW] * w1;
    }
    __shared__ float red[4][14];
    int lane = threadIdx.x & 63, wid = threadIdx.x >> 6;
#pragma unroll
    for (int i = 0; i < 14; i++) {
        float v = acc[i];
        for (int off = 32; off > 0; off >>= 1) v += __shfl_down(v, off, 64);
        if (lane == 0) red[wid][i] = v;
    }
    __syncthreads();
    if (threadIdx.x < 14) {
        float s = red[0][threadIdx.x] + red[1][threadIdx.x] +
                  red[2][threadIdx.x] + red[3][threadIdx.x];
        ws[512 + (b * NBLK + bx) * 16 + threadIdx.x] = s;
    }
}

// Reduce vote partials -> M matrices; init minmax keys.
__global__ void k_build(float* __restrict__ ws) {
    __shared__ float votes[64];
    int tid = threadIdx.x;
    if (tid < 56) {
        int b = tid / 14, i = tid % 14;
        const float* part = ws + 512 + (size_t)b * NBLK * 16 + i;
        float s = 0.f;
        for (int blk = 0; blk < NBLK; blk++) s += part[blk * 16];
        votes[b * 16 + i] = s;
    }
    __syncthreads();
    if (tid < 12) {
        int b = tid / 3, k = tid % 3;
        float lp0 = 0, lp1 = 0, lp2 = 0, rp0 = 0, rp1 = 0, rp2 = 0;
        if (k > 0) {
            const float* v = votes + b * 16 + (k - 1) * 7;
            float d = v[0] + 1e-5f;
            lp0 = v[1] / d; lp1 = v[2] / d; lp2 = v[3] / d;
            rp0 = v[4] / d; rp1 = v[5] / d; rp2 = v[6] / d;
        }
        float rx = -rp0, ry = -rp1, rz = -rp2;
        float ang = sqrtf(rx * rx + ry * ry + rz * rz) + 1e-8f;
        float ax = rx / ang, ay = ry / ang, az = rz / ang;
        float K[3][3] = {{0.f, -az, ay}, {az, 0.f, -ax}, {-ay, ax, 0.f}};
        float c = cosf(ang), s = sinf(ang);
        float K2[3][3], Rm[3][3];
#pragma unroll
        for (int i = 0; i < 3; i++)
#pragma unroll
            for (int j = 0; j < 3; j++)
                K2[i][j] = K[i][0] * K[0][j] + K[i][1] * K[1][j] + K[i][2] * K[2][j];
#pragma unroll
        for (int i = 0; i < 3; i++)
#pragma unroll
            for (int j = 0; j < 3; j++)
                Rm[i][j] = (i == j ? 1.f : 0.f) + s * K[i][j] + (1.f - c) * K2[i][j];
        float t0 = lp0, t1 = lp1, t2 = lp2;
        float* M = ws + 64 + (b * 3 + k) * 12;
#pragma unroll
        for (int i = 0; i < 3; i++) {
            M[i * 4 + 0] = Rm[i][0]; M[i * 4 + 1] = Rm[i][1]; M[i * 4 + 2] = Rm[i][2];
            float tt = (i == 0 ? t0 : (i == 1 ? t1 : t2));
            M[i * 4 + 3] = tt - (Rm[i][0] * t0 + Rm[i][1] * t1 + Rm[i][2] * t2);
        }
    }
    if (tid >= 12 && tid < 36) {
        int s2 = tid - 12;
        unsigned* keys = (unsigned*)(ws + 256);
        keys[s2] = ((s2 % 6) < 3) ? fkey(BIGF) : fkey(-BIGF);
    }
}

__global__ __launch_bounds__(256) void k_minmax(const float* __restrict__ in,
                                                float* __restrict__ ws) {
    const int b = blockIdx.y;
    const int p = blockIdx.x * 256 + threadIdx.x;
    const float* ib = in + (size_t)b * NCH * HW + p;
    const float* Mb = ws + 64 + b * 36;
    float mn[3] = {BIGF, BIGF, BIGF}, mx[3] = {-BIGF, -BIGF, -BIGF};
    float m = sigmoidf_(ib[(size_t)3 * HW]);
    if (m > THRESHF) {
        float v0 = ib[(size_t)16 * HW], v1 = ib[(size_t)17 * HW];
        float v2 = ib[(size_t)18 * HW], v3 = ib[(size_t)19 * HW];
        int am = 0; float bb = v0;
        if (v1 > bb) { bb = v1; am = 1; }
        if (v2 > bb) { bb = v2; am = 2; }
        if (v3 > bb) { bb = v3; am = 3; }
        float px = 0.f, py = 0.f, pz = 0.f;
        if (am > 0) {
            const float* Mk = Mb + (am - 1) * 12;
            float a = ib[0], bq = ib[(size_t)HW], cq = ib[(size_t)2 * HW];
            px = Mk[0] * a + Mk[1] * bq + Mk[2]  * cq + Mk[3];
            py = Mk[4] * a + Mk[5] * bq + Mk[6]  * cq + Mk[7];
            pz = Mk[8] * a + Mk[9] * bq + Mk[10] * cq + Mk[11];
        }
        mn[0] = px; mn[1] = py; mn[2] = pz;
        mx[0] = px; mx[1] = py; mx[2] = pz;
    }
    __shared__ float rmn[4][3], rmx[4][3];
    int lane = threadIdx.x & 63, wid = threadIdx.x >> 6;
#pragma unroll
    for (int i = 0; i < 3; i++) {
        float v = mn[i];
        for (int off = 32; off > 0; off >>= 1) v = fminf(v, __shfl_down(v, off, 64));
        if (lane == 0) rmn[wid][i] = v;
        float u = mx[i];
        for (int off = 32; off > 0; off >>= 1) u = fmaxf(u, __shfl_down(u, off, 64));
        if (lane == 0) rmx[wid][i] = u;
    }
    __syncthreads();
    unsigned* keys = (unsigned*)(ws + 256);
    if (threadIdx.x < 3) {
        int i = threadIdx.x;
        float v = fminf(fminf(rmn[0][i], rmn[1][i]), fminf(rmn[2][i], rmn[3][i]));
        atomicMin(&keys[b * 6 + i], fkey(v));
    } else if (threadIdx.x < 6) {
        int i = threadIdx.x - 3;
        float v = fmaxf(fmaxf(rmx[0][i], rmx[1][i]), fmaxf(rmx[2][i], rmx[3][i]));
        atomicMax(&keys[b * 6 + 3 + i], fkey(v));
    }
}

__global__ void k_prep(float* __restrict__ ws) {
    int b = threadIdx.x;
    if (b < NB) {
        const unsigned* keys = (const unsigned*)(ws + 256);
        float l0 = funkey(keys[b * 6 + 0]), l1 = funkey(keys[b * 6 + 1]), l2 = funkey(keys[b * 6 + 2]);
        float u0 = funkey(keys[b * 6 + 3]), u1 = funkey(keys[b * 6 + 4]), u2 = funkey(keys[b * 6 + 5]);
        float scale = fmaxf(u0 - l0, fmaxf(u1 - l1, u2 - l2));
        float safe = (scale == 0.f) ? 1.f : scale;
        bool flag = scale != 0.f;
        float* pr = ws + 288 + b * 8;
        pr[0] = l0; pr[1] = l1; pr[2] = l2; pr[3] = safe;
        pr[4] = flag ? 1.f : 0.f;
        float q0 = flag ? (0.f - l0) / safe : 0.f;
        float q1 = flag ? (0.f - l1) / safe : 0.f;
        float q2 = flag ? (0.f - l2) / safe : 0.f;
        int fl0 = vox1(q0) * 1024 + vox1(q1) * 32 + vox1(q2);
        ((int*)pr)[5] = fl0;
    }
}

// THE big kernel: produces all 89 out_cat channels + voxel scatter.
// Block = 256 pixels, 1 pixel/thread. Feat channels staged through LDS for
// wave-per-pixel (lane = channel) line-coherent atomics into tmp[b][vox][64].
template<bool VOXMAJOR>
__global__ __launch_bounds__(256) void k_scatter_all(const float* __restrict__ in,
                                                     float* __restrict__ out,
                                                     float* __restrict__ dst,
                                                     const float* __restrict__ ws) {
    __shared__ float tile[64][257];
    __shared__ float accz[4][64];
    const int b = blockIdx.y;
    const int tid = threadIdx.x;
    const int p = blockIdx.x * 256 + tid;
    const int lane = tid & 63, w = tid >> 6;
    const float* ib = in + (size_t)b * NCH * HW + p;
    float* ob = out + (size_t)b * OCH * HW + p;
    const float* Mb = ws + 64 + b * 36;
    const float* pr = ws + 288 + b * 8;
    const float l0 = pr[0], l1 = pr[1], l2 = pr[2], safe = pr[3];
    const bool flag = pr[4] != 0.f;
    const int fl0 = ((const int*)pr)[5];

    // overhead channels: load once, copy out, compute per-pixel info
    float n0 = ib[0], n1 = ib[(size_t)HW], n2 = ib[(size_t)2 * HW];
    float mvv = ib[(size_t)3 * HW];
    float g0 = ib[(size_t)16 * HW], g1 = ib[(size_t)17 * HW];
    float g2 = ib[(size_t)18 * HW], g3 = ib[(size_t)19 * HW];
    __builtin_nontemporal_store(n0,  &ob[0]);
    __builtin_nontemporal_store(n1,  &ob[(size_t)HW]);
    __builtin_nontemporal_store(n2,  &ob[(size_t)2 * HW]);
    __builtin_nontemporal_store(mvv, &ob[(size_t)3 * HW]);
#pragma unroll
    for (int c = 4; c < 16; c++) {
        float v = __builtin_nontemporal_load(&ib[(size_t)c * HW]);
        __builtin_nontemporal_store(v, &ob[(size_t)c * HW]);
    }
    __builtin_nontemporal_store(g0, &ob[(size_t)16 * HW]);
    __builtin_nontemporal_store(g1, &ob[(size_t)17 * HW]);
    __builtin_nontemporal_store(g2, &ob[(size_t)18 * HW]);
    __builtin_nontemporal_store(g3, &ob[(size_t)19 * HW]);
#pragma unroll
    for (int c = 20; c < 22; c++) {
        float v = __builtin_nontemporal_load(&ib[(size_t)c * HW]);
        __builtin_nontemporal_store(v, &ob[(size_t)c * HW]);
    }

    float m = sigmoidf_(mvv);
    bool masked = m > THRESHF;
    int am = 0;
    {
        float bb = g0;
        if (g1 > bb) { bb = g1; am = 1; }
        if (g2 > bb) { bb = g2; am = 2; }
        if (g3 > bb) { bb = g3; am = 3; }
    }
    bool glb  = masked && (am != 0);
    bool spec = masked && (am == 0);
    float px = 0.f, py = 0.f, pz = 0.f;
    if (am > 0) {
        const float* Mk = Mb + (am - 1) * 12;
        px = Mk[0] * n0 + Mk[1] * n1 + Mk[2]  * n2 + Mk[3];
        py = Mk[4] * n0 + Mk[5] * n1 + Mk[6]  * n2 + Mk[7];
        pz = Mk[8] * n0 + Mk[9] * n1 + Mk[10] * n2 + Mk[11];
    }
    float qx, qy, qz;
    if (flag) { qx = (px - l0) / safe; qy = (py - l1) / safe; qz = (pz - l2) / safe; }
    else      { qx = px; qy = py; qz = pz; }
    float ox = masked ? qx : 0.f, oy = masked ? qy : 0.f, oz = masked ? qz : 0.f;
    __builtin_nontemporal_store(ox, &ob[(size_t)86 * HW]);
    __builtin_nontemporal_store(oy, &ob[(size_t)87 * HW]);
    __builtin_nontemporal_store(oz, &ob[(size_t)88 * HW]);
    int flat = glb ? (vox1(ox) * 1024 + vox1(oy) * 32 + vox1(oz)) : fl0;

    // feat channels: copy + LDS stage
#pragma unroll 8
    for (int c = 0; c < 64; c++) {
        float v = __builtin_nontemporal_load(&ib[(size_t)(22 + c) * HW]);
        tile[c][tid] = v;
        __builtin_nontemporal_store(v, &ob[(size_t)(22 + c) * HW]);
    }

    unsigned long long gm = __ballot(glb);
    unsigned long long sm = __ballot(spec);
    __syncthreads();

    while (gm) {
        int i = __ffsll(gm) - 1; gm &= gm - 1;
        int fl = __shfl(flat, i, 64);
        float v = tile[lane][w * 64 + i];
        if (VOXMAJOR)
            atomicAdd(&dst[(((size_t)b * VOX + fl) << 6) + lane], v);
        else
            atomicAdd(&dst[(((size_t)(b * 64 + lane)) << 15) + fl], v);
    }
    float sacc = 0.f;
    while (sm) {
        int i = __ffsll(sm) - 1; sm &= sm - 1;
        sacc += tile[lane][w * 64 + i];
    }
    accz[w][lane] = sacc;
    __syncthreads();
    if (tid < 64) {
        float s = accz[0][tid] + accz[1][tid] + accz[2][tid] + accz[3][tid];
        if (s != 0.f) {
            if (VOXMAJOR)
                atomicAdd(&dst[(((size_t)b * VOX + fl0) << 6) + tid], s);
            else
                atomicAdd(&dst[(((size_t)(b * 64 + tid)) << 15) + fl0], s);
        }
    }
}

// tmp[b][vox][64] -> occ[b][64][vox], 64-voxel tiles via LDS.
__global__ __launch_bounds__(256) void k_transpose(const float* __restrict__ tmp,
                                                   float* __restrict__ occ) {
    __shared__ float ld[64][65];
    const int b = blockIdx.y;
    const int vox0 = blockIdx.x * 64;
    const int t = threadIdx.x;
    const int v = t & 63, g = t >> 6;
    const float* src = tmp + (((size_t)b * VOX + vox0 + v) << 6) + g * 16;
#pragma unroll
    for (int i = 0; i < 4; i++) {
        f4 x = *(const f4*)(src + 4 * i);
        ld[g * 16 + 4 * i + 0][v] = x[0];
        ld[g * 16 + 4 * i + 1][v] = x[1];
        ld[g * 16 + 4 * i + 2][v] = x[2];
        ld[g * 16 + 4 * i + 3][v] = x[3];
    }
    __syncthreads();
    const int f = t >> 2;
    float* dstp = occ + (((size_t)(b * 64 + f)) << 15) + vox0;
#pragma unroll
    for (int i = 0; i < 4; i++) {
        int mq = (t & 3) * 4 + i;
        f4 x;
        x[0] = ld[f][4 * mq + 0]; x[1] = ld[f][4 * mq + 1];
        x[2] = ld[f][4 * mq + 2]; x[3] = ld[f][4 * mq + 3];
        __builtin_nontemporal_store(x, (f4*)(dstp + 4 * mq));
    }
}

extern "C" void kernel_launch(void* const* d_in, const int* in_sizes, int n_in,
                              void* d_out, int out_size, void* d_ws, size_t ws_size,
                              hipStream_t stream) {
    const float* in = (const float*)d_in[0];
    float* out = (float*)d_out;
    float* ws = (float*)d_ws;
    float* occ = out + (size_t)NB * OCH * HW;
    float* tmp = ws + 32768;
    const size_t tmp_bytes = (size_t)NB * VOX * 64 * sizeof(float);
    const bool voxmajor = ws_size >= 32768 * sizeof(float) + tmp_bytes;
    const unsigned n4 = (unsigned)(tmp_bytes / 16);

    dim3 gv(NBLK, NB);
    if (voxmajor) k_votes_zero<<<gv, 256, 0, stream>>>(in, ws, (f4*)tmp, n4);
    else          k_votes_zero<<<gv, 256, 0, stream>>>(in, ws, (f4*)occ, n4);
    k_build <<<1, 64, 0, stream>>>(ws);
    k_minmax<<<gv, 256, 0, stream>>>(in, ws);
    k_prep  <<<1, 64, 0, stream>>>(ws);
    if (voxmajor) {
        k_scatter_all<true> <<<gv, 256, 0, stream>>>(in, out, tmp, ws);
        dim3 gt(VOX / 64, NB);
        k_transpose<<<gt, 256, 0, stream>>>(tmp, occ);
    } else {
        k_scatter_all<false><<<gv, 256, 0, stream>>>(in, out, occ, ws);
    }
}

// Round 6
// 143.002 us; speedup vs baseline: 1.5743x; 1.1757x over previous
//
#include <hip/hip_runtime.h>
#include <math.h>

#define HW     76800
#define HW4    19200
#define NCH    86
#define OCH    89
#define NB     4
#define VOX    32768
#define NBLKV  75         // f4 blocks per batch for votes/minmax (1024 px each)
#define THRESHF 0.7f
#define BIGF   1e30f

typedef float f4 __attribute__((ext_vector_type(4)));

// ws float layout:
// [64..207]   M: (b*3 + k)*12 row-major 3x4 [R|t]     (written by k_minmax bx==0)
// [256..279]  minmax keys (uint32): b*6 + c           (init by k_votes_zero blk(0,0))
// [512..5312) vote partials: (b*75+bx)*16 + i, i<14   (k_votes_zero)
// [32768..]   occ_tmp: [b][vox][64] voxel-major scratch (33.5 MB)

__device__ __forceinline__ float sigmoidf_(float x) {
    if (x >= 0.f) { return 1.f / (1.f + expf(-x)); }
    float e = expf(x); return e / (1.f + e);
}
__device__ __forceinline__ unsigned fkey(float f) {
    unsigned u = __float_as_uint(f);
    return (u & 0x80000000u) ? ~u : (u | 0x80000000u);
}
__device__ __forceinline__ float funkey(unsigned k) {
    unsigned u = (k & 0x80000000u) ? (k ^ 0x80000000u) : ~k;
    return __uint_as_float(u);
}
__device__ __forceinline__ int vox1(float q) {
    int v = (int)floorf(q * 32.f);
    return v < 0 ? 0 : (v > 31 ? 31 : v);
}

// votes (f4, per-block partials) + zero occ_tmp + init minmax keys
__global__ __launch_bounds__(256) void k_votes_zero(const f4* __restrict__ in4,
                                                    float* __restrict__ ws,
                                                    f4* __restrict__ zp, unsigned n4) {
    const int b = blockIdx.y, bx = blockIdx.x;
    const int tid = threadIdx.x;
    {   // zero slice of scratch
        unsigned gid = ((unsigned)(b * NBLKV + bx)) * 256u + tid;
        f4 z = {0.f, 0.f, 0.f, 0.f};
        for (unsigned i = gid; i < n4; i += NB * NBLKV * 256u)
            __builtin_nontemporal_store(z, &zp[i]);
    }
    if (b == 0 && bx == 0 && tid < 24) {
        unsigned* keys = (unsigned*)(ws + 256);
        keys[tid] = ((tid % 6) < 3) ? fkey(BIGF) : fkey(-BIGF);
    }
    const size_t ib = (size_t)b * NCH * HW4 + bx * 256 + tid;
    f4 mv = in4[ib + (size_t)3 * HW4];
    f4 c0 = in4[ib + (size_t)20 * HW4];
    f4 c1 = in4[ib + (size_t)21 * HW4];
    f4 L[12];
#pragma unroll
    for (int i = 0; i < 12; i++) L[i] = in4[ib + (size_t)(4 + i) * HW4];
    float acc[14];
#pragma unroll
    for (int i = 0; i < 14; i++) acc[i] = 0.f;
#pragma unroll
    for (int k = 0; k < 4; k++) {
        float m  = sigmoidf_(mv[k]);
        float s0 = sigmoidf_(c0[k]) * m;
        float s1 = sigmoidf_(c1[k]) * m;
        float w0 = m * s0, w1 = m * s1;
        acc[0] += s0; acc[7] += s1;
#pragma unroll
        for (int c = 0; c < 3; c++) {
            acc[1 + c]  += L[c][k]     * w0;
            acc[8 + c]  += L[3 + c][k] * w1;
            acc[4 + c]  += L[6 + c][k] * w0;
            acc[11 + c] += L[9 + c][k] * w1;
        }
    }
    __shared__ float red[4][14];
    int lane = tid & 63, wid = tid >> 6;
#pragma unroll
    for (int i = 0; i < 14; i++) {
        float v = acc[i];
        for (int off = 32; off > 0; off >>= 1) v += __shfl_down(v, off, 64);
        if (lane == 0) red[wid][i] = v;
    }
    __syncthreads();
    if (tid < 14)
        ws[512 + (b * NBLKV + bx) * 16 + tid] =
            red[0][tid] + red[1][tid] + red[2][tid] + red[3][tid];
}

// build (redundant per block, from partials) + per-pixel minmax (f4)
__global__ __launch_bounds__(256) void k_minmax(const f4* __restrict__ in4,
                                                float* __restrict__ ws) {
    __shared__ float vsh[14];
    __shared__ float Msh[36];
    const int b = blockIdx.y, bx = blockIdx.x, tid = threadIdx.x;
    if (tid < 14) {
        const float* part = ws + 512 + (size_t)b * NBLKV * 16 + tid;
        float s = 0.f;
#pragma unroll 5
        for (int blk = 0; blk < NBLKV; blk++) s += part[blk * 16];
        vsh[tid] = s;
    }
    __syncthreads();
    if (tid < 3) {
        int k = tid;
        float lp0 = 0, lp1 = 0, lp2 = 0, rp0 = 0, rp1 = 0, rp2 = 0;
        if (k > 0) {
            const float* v = vsh + (k - 1) * 7;
            float d = v[0] + 1e-5f;
            lp0 = v[1] / d; lp1 = v[2] / d; lp2 = v[3] / d;
            rp0 = v[4] / d; rp1 = v[5] / d; rp2 = v[6] / d;
        }
        float rx = -rp0, ry = -rp1, rz = -rp2;
        float ang = sqrtf(rx * rx + ry * ry + rz * rz) + 1e-8f;
        float ax = rx / ang, ay = ry / ang, az = rz / ang;
        float K[3][3] = {{0.f, -az, ay}, {az, 0.f, -ax}, {-ay, ax, 0.f}};
        float c = cosf(ang), s = sinf(ang);
        float K2[3][3], Rm[3][3];
#pragma unroll
        for (int i = 0; i < 3; i++)
#pragma unroll
            for (int j = 0; j < 3; j++)
                K2[i][j] = K[i][0] * K[0][j] + K[i][1] * K[1][j] + K[i][2] * K[2][j];
#pragma unroll
        for (int i = 0; i < 3; i++)
#pragma unroll
            for (int j = 0; j < 3; j++)
                Rm[i][j] = (i == j ? 1.f : 0.f) + s * K[i][j] + (1.f - c) * K2[i][j];
#pragma unroll
        for (int i = 0; i < 3; i++) {
            float tt = (i == 0 ? lp0 : (i == 1 ? lp1 : lp2));
            float tr = tt - (Rm[i][0] * lp0 + Rm[i][1] * lp1 + Rm[i][2] * lp2);
            Msh[k * 12 + i * 4 + 0] = Rm[i][0];
            Msh[k * 12 + i * 4 + 1] = Rm[i][1];
            Msh[k * 12 + i * 4 + 2] = Rm[i][2];
            Msh[k * 12 + i * 4 + 3] = tr;
            if (bx == 0) {
                float* M = ws + 64 + (b * 3 + k) * 12;
                M[i * 4 + 0] = Rm[i][0]; M[i * 4 + 1] = Rm[i][1];
                M[i * 4 + 2] = Rm[i][2]; M[i * 4 + 3] = tr;
            }
        }
    }
    __syncthreads();

    const size_t ib = (size_t)b * NCH * HW4 + bx * 256 + tid;
    f4 n0 = in4[ib], n1 = in4[ib + HW4], n2 = in4[ib + 2 * HW4];
    f4 mv = in4[ib + 3 * HW4];
    f4 g0 = in4[ib + 16 * HW4], g1 = in4[ib + 17 * HW4];
    f4 g2 = in4[ib + 18 * HW4], g3 = in4[ib + 19 * HW4];
    float mn[3] = {BIGF, BIGF, BIGF}, mx[3] = {-BIGF, -BIGF, -BIGF};
#pragma unroll
    for (int k = 0; k < 4; k++) {
        float m = sigmoidf_(mv[k]);
        if (!(m > THRESHF)) continue;
        int am = 0; float bb = g0[k];
        if (g1[k] > bb) { bb = g1[k]; am = 1; }
        if (g2[k] > bb) { bb = g2[k]; am = 2; }
        if (g3[k] > bb) { bb = g3[k]; am = 3; }
        float px = 0.f, py = 0.f, pz = 0.f;
        if (am > 0) {
            const float* Mk = Msh + (am - 1) * 12;
            float a = n0[k], bq = n1[k], cq = n2[k];
            px = Mk[0] * a + Mk[1] * bq + Mk[2]  * cq + Mk[3];
            py = Mk[4] * a + Mk[5] * bq + Mk[6]  * cq + Mk[7];
            pz = Mk[8] * a + Mk[9] * bq + Mk[10] * cq + Mk[11];
        }
        mn[0] = fminf(mn[0], px); mn[1] = fminf(mn[1], py); mn[2] = fminf(mn[2], pz);
        mx[0] = fmaxf(mx[0], px); mx[1] = fmaxf(mx[1], py); mx[2] = fmaxf(mx[2], pz);
    }
    __shared__ float rmn[4][3], rmx[4][3];
    int lane = tid & 63, wid = tid >> 6;
#pragma unroll
    for (int i = 0; i < 3; i++) {
        float v = mn[i];
        for (int off = 32; off > 0; off >>= 1) v = fminf(v, __shfl_down(v, off, 64));
        if (lane == 0) rmn[wid][i] = v;
        float u = mx[i];
        for (int off = 32; off > 0; off >>= 1) u = fmaxf(u, __shfl_down(u, off, 64));
        if (lane == 0) rmx[wid][i] = u;
    }
    __syncthreads();
    unsigned* keys = (unsigned*)(ws + 256);
    if (tid < 3) {
        float v = fminf(fminf(rmn[0][tid], rmn[1][tid]), fminf(rmn[2][tid], rmn[3][tid]));
        atomicMin(&keys[b * 6 + tid], fkey(v));
    } else if (tid < 6) {
        int i = tid - 3;
        float v = fmaxf(fmaxf(rmx[0][i], rmx[1][i]), fmaxf(rmx[2][i], rmx[3][i]));
        atomicMax(&keys[b * 6 + 3 + i], fkey(v));
    }
}

// all 89 out_cat channels + voxel scatter. 256 px/block.
// Global traffic fully f4: wave w copies its channel set (64 f4 = full channel
// slice per wave-instruction, 1KB coalesced); feat staged to LDS for
// wave-per-pixel (lane = channel) line-coherent atomics.
template<bool VOXMAJOR>
__global__ __launch_bounds__(256) void k_scatter_all(const f4* __restrict__ in4,
                                                     f4* __restrict__ out4,
                                                     float* __restrict__ dst,
                                                     const float* __restrict__ ws) {
    __shared__ float tile[64][257];
    __shared__ float accz[4][64];
    const int b = blockIdx.y, blk = blockIdx.x;
    const int tid = threadIdx.x, lane = tid & 63, w = tid >> 6;
    const size_t ib4 = (size_t)b * NCH * HW4 + blk * 64;
    const size_t ob4 = (size_t)b * OCH * HW4 + blk * 64;

    // prep decode (uniform per thread, ~30 VALU)
    const unsigned* keys = (const unsigned*)(ws + 256);
    float l0 = funkey(keys[b * 6 + 0]), l1 = funkey(keys[b * 6 + 1]), l2 = funkey(keys[b * 6 + 2]);
    float u0 = funkey(keys[b * 6 + 3]), u1 = funkey(keys[b * 6 + 4]), u2 = funkey(keys[b * 6 + 5]);
    float scale = fmaxf(u0 - l0, fmaxf(u1 - l1, u2 - l2));
    float safe = (scale == 0.f) ? 1.f : scale;
    bool flag = scale != 0.f;
    float z0 = flag ? (0.f - l0) / safe : 0.f;
    float z1 = flag ? (0.f - l1) / safe : 0.f;
    float z2 = flag ? (0.f - l2) / safe : 0.f;
    const int fl0 = vox1(z0) * 1024 + vox1(z1) * 32 + vox1(z2);

    // phase A: copy ch 0..21 (regular loads -> lines stay L2-hot for phase C)
    for (int c = w; c < 22; c += 4) {
        f4 v = in4[ib4 + (size_t)c * HW4 + lane];
        __builtin_nontemporal_store(v, &out4[ob4 + (size_t)c * HW4 + lane]);
    }
    // phase B: feat ch 22..85: NT copy + LDS stage
#pragma unroll 4
    for (int i = 0; i < 16; i++) {
        int c = w * 16 + i;
        f4 v = __builtin_nontemporal_load(&in4[ib4 + (size_t)(22 + c) * HW4 + lane]);
        __builtin_nontemporal_store(v, &out4[ob4 + (size_t)(22 + c) * HW4 + lane]);
        tile[c][4 * lane + 0] = v[0]; tile[c][4 * lane + 1] = v[1];
        tile[c][4 * lane + 2] = v[2]; tile[c][4 * lane + 3] = v[3];
    }

    // phase C: per-pixel info (px = blk*256 + tid), scalar L2-hot reads
    const float* ibs = (const float*)in4 + (size_t)b * NCH * HW + blk * 256 + tid;
    float* obs = (float*)out4 + (size_t)b * OCH * HW + blk * 256 + tid;
    float n0 = ibs[0], n1 = ibs[(size_t)HW], n2 = ibs[(size_t)2 * HW];
    float mvv = ibs[(size_t)3 * HW];
    float g0 = ibs[(size_t)16 * HW], g1 = ibs[(size_t)17 * HW];
    float g2 = ibs[(size_t)18 * HW], g3 = ibs[(size_t)19 * HW];
    float m = sigmoidf_(mvv);
    bool masked = m > THRESHF;
    int am = 0;
    { float bb = g0;
      if (g1 > bb) { bb = g1; am = 1; }
      if (g2 > bb) { bb = g2; am = 2; }
      if (g3 > bb) { bb = g3; am = 3; } }
    bool glb  = masked && (am != 0);
    bool spec = masked && (am == 0);
    float px = 0.f, py = 0.f, pz = 0.f;
    if (am > 0) {
        const float* Mk = ws + 64 + b * 36 + (am - 1) * 12;
        px = Mk[0] * n0 + Mk[1] * n1 + Mk[2]  * n2 + Mk[3];
        py = Mk[4] * n0 + Mk[5] * n1 + Mk[6]  * n2 + Mk[7];
        pz = Mk[8] * n0 + Mk[9] * n1 + Mk[10] * n2 + Mk[11];
    }
    float qx, qy, qz;
    if (flag) { qx = (px - l0) / safe; qy = (py - l1) / safe; qz = (pz - l2) / safe; }
    else      { qx = px; qy = py; qz = pz; }
    float ox = masked ? qx : 0.f, oy = masked ? qy : 0.f, oz = masked ? qz : 0.f;
    __builtin_nontemporal_store(ox, &obs[(size_t)86 * HW]);
    __builtin_nontemporal_store(oy, &obs[(size_t)87 * HW]);
    __builtin_nontemporal_store(oz, &obs[(size_t)88 * HW]);
    int flat = glb ? (vox1(ox) * 1024 + vox1(oy) * 32 + vox1(oz)) : fl0;

    unsigned long long gm = __ballot(glb);
    unsigned long long sm = __ballot(spec);
    __syncthreads();   // tile ready

    float* occb = dst;
    while (gm) {
        int i = __ffsll(gm) - 1; gm &= gm - 1;
        int fl = __shfl(flat, i, 64);
        float v = tile[lane][w * 64 + i];
        if (VOXMAJOR)
            atomicAdd(&occb[(((size_t)b * VOX + fl) << 6) + lane], v);
        else
            atomicAdd(&occb[(((size_t)(b * 64 + lane)) << 15) + fl], v);
    }
    float sacc = 0.f;
    while (sm) {
        int i = __ffsll(sm) - 1; sm &= sm - 1;
        sacc += tile[lane][w * 64 + i];
    }
    accz[w][lane] = sacc;
    __syncthreads();
    if (tid < 64) {
        float s = accz[0][tid] + accz[1][tid] + accz[2][tid] + accz[3][tid];
        if (s != 0.f) {
            if (VOXMAJOR)
                atomicAdd(&occb[(((size_t)b * VOX + fl0) << 6) + tid], s);
            else
                atomicAdd(&occb[(((size_t)(b * 64 + tid)) << 15) + fl0], s);
        }
    }
}

// tmp[b][vox][64] -> occ[b][64][vox]
__global__ __launch_bounds__(256) void k_transpose(const float* __restrict__ tmp,
                                                   float* __restrict__ occ) {
    __shared__ float ld[64][65];
    const int b = blockIdx.y;
    const int vox0 = blockIdx.x * 64;
    const int t = threadIdx.x;
    const int v = t & 63, g = t >> 6;
    const float* src = tmp + (((size_t)b * VOX + vox0 + v) << 6) + g * 16;
#pragma unroll
    for (int i = 0; i < 4; i++) {
        f4 x = *(const f4*)(src + 4 * i);
        ld[g * 16 + 4 * i + 0][v] = x[0];
        ld[g * 16 + 4 * i + 1][v] = x[1];
        ld[g * 16 + 4 * i + 2][v] = x[2];
        ld[g * 16 + 4 * i + 3][v] = x[3];
    }
    __syncthreads();
    const int f = t >> 2;
    float* dstp = occ + (((size_t)(b * 64 + f)) << 15) + vox0;
#pragma unroll
    for (int i = 0; i < 4; i++) {
        int mq = (t & 3) * 4 + i;
        f4 x;
        x[0] = ld[f][4 * mq + 0]; x[1] = ld[f][4 * mq + 1];
        x[2] = ld[f][4 * mq + 2]; x[3] = ld[f][4 * mq + 3];
        __builtin_nontemporal_store(x, (f4*)(dstp + 4 * mq));
    }
}

extern "C" void kernel_launch(void* const* d_in, const int* in_sizes, int n_in,
                              void* d_out, int out_size, void* d_ws, size_t ws_size,
                              hipStream_t stream) {
    const f4* in4 = (const f4*)d_in[0];
    float* out = (float*)d_out;
    float* ws = (float*)d_ws;
    float* occ = out + (size_t)NB * OCH * HW;
    float* tmp = ws + 32768;
    const size_t tmp_bytes = (size_t)NB * VOX * 64 * sizeof(float);
    const bool voxmajor = ws_size >= 32768 * sizeof(float) + tmp_bytes;
    const unsigned n4 = (unsigned)(tmp_bytes / 16);

    dim3 g75(NBLKV, NB);
    if (voxmajor) k_votes_zero<<<g75, 256, 0, stream>>>(in4, ws, (f4*)tmp, n4);
    else          k_votes_zero<<<g75, 256, 0, stream>>>(in4, ws, (f4*)occ, n4);
    k_minmax<<<g75, 256, 0, stream>>>(in4, ws);
    dim3 gs(300, NB);
    if (voxmajor) {
        k_scatter_all<true><<<gs, 256, 0, stream>>>(in4, (f4*)out, tmp, ws);
        dim3 gt(VOX / 64, NB);
        k_transpose<<<gt, 256, 0, stream>>>(tmp, occ);
    } else {
        k_scatter_all<false><<<gs, 256, 0, stream>>>(in4, (f4*)out, occ, ws);
    }
}